// Round 1
// baseline (112.456 us; speedup 1.0000x reference)
//
#include <hip/hip_runtime.h>
#include <hip/hip_bf16.h>

// GEMM view: Out[(b,d), c] = sum_k A[(b,d),k] * Bk[k,c]
//   row = b*32 + d   (M = 131072)
//   k   = i*32 + j   (K = 1024)  -> MFMA step s covers i=s, j=0..31
//   col = c          (N = 64)
// A[(b,d), i*32+j] = x[b,i,d] * y[b,j,d]  (generated in registers)
// Bk[i*32+j, c]    = kernel[c,i,j]        (pre-swizzled to bf16 B-frag order)

typedef __attribute__((ext_vector_type(8))) short short8;
typedef __attribute__((ext_vector_type(4))) float f32x4;

__device__ __forceinline__ unsigned short f2bf_rne(float f) {
    union { float f; unsigned u; } w; w.f = f;
    return (unsigned short)((w.u + 0x7FFFu + ((w.u >> 16) & 1u)) >> 16);
}

// Pre-kernel: kernel[c][i][j] (f32) -> kswz bf16 in B-fragment order:
// kswz[(((s*4 + nt)*64 + lane)*8 + t)] = bf16(kernel[c = nt*16 + (lane&15)][s][(lane>>4)*8 + t])
__global__ __launch_bounds__(256) void kswz_kernel(const float* __restrict__ kern,
                                                   short* __restrict__ kswz) {
    int idx  = blockIdx.x * 256 + threadIdx.x;  // 8192 total: (s, nt, lane)
    int lane = idx & 63;
    int nt   = (idx >> 6) & 3;
    int s    = idx >> 8;
    int c    = nt * 16 + (lane & 15);
    int jb   = (lane >> 4) * 8;
    const float* src = kern + c * 1024 + s * 32 + jb;
    short8 v;
#pragma unroll
    for (int t = 0; t < 8; ++t) v[t] = (short)f2bf_rne(src[t]);
    *(short8*)(kswz + (size_t)idx * 8) = v;
}

// Main: 512 blocks x 256 threads. Block stages x for 8 b's in LDS.
// Wave w handles b0 = blk*8 + w*2 .. b0+1: 4 M-tiles of 16 rows (d-halves).
__global__ __launch_bounds__(256) void cin_main(const float* __restrict__ x,
                                                const float* __restrict__ y,
                                                const short* __restrict__ kswz,
                                                float* __restrict__ out_mat,
                                                float* __restrict__ out_fin) {
    __shared__ float xs[8 * 1024];  // 32 KB: x[b_blk..b_blk+8)[i][d]

    const int tid  = threadIdx.x;
    const int wave = tid >> 6;
    const int lane = tid & 63;
    const int quad = lane >> 4;
    const int n16  = lane & 15;
    const int b_blk = blockIdx.x * 8;

    // cooperative x stage: 8 * 1024 floats = 2048 float4
    {
        const float4* xg = (const float4*)(x + (size_t)b_blk * 1024);
        float4* xs4 = (float4*)xs;
#pragma unroll
        for (int i = 0; i < 8; ++i) xs4[tid + 256 * i] = xg[tid + 256 * i];
    }
    __syncthreads();

    const int b0 = b_blk + wave * 2;

    // preload y fragments: yv[mt][t] = y[b, j = quad*8+t, d]
    float yv[4][8];
#pragma unroll
    for (int mt = 0; mt < 4; ++mt) {
        const int b = b0 + (mt >> 1);
        const int d = n16 + 16 * (mt & 1);
        const float* yp = y + (size_t)b * 1024 + (quad * 8) * 32 + d;
#pragma unroll
        for (int t = 0; t < 8; ++t) yv[mt][t] = yp[t * 32];
    }

    f32x4 acc[4][4];
#pragma unroll
    for (int mt = 0; mt < 4; ++mt)
#pragma unroll
        for (int nt = 0; nt < 4; ++nt) acc[mt][nt] = (f32x4){0.f, 0.f, 0.f, 0.f};

    const short8* kp = (const short8*)kswz;  // index: (s*4 + nt)*64 + lane

    for (int s = 0; s < 32; ++s) {
        short8 bfrag[4];
#pragma unroll
        for (int nt = 0; nt < 4; ++nt) bfrag[nt] = kp[(s * 4 + nt) * 64 + lane];

#pragma unroll
        for (int mt = 0; mt < 4; ++mt) {
            const int bl = wave * 2 + (mt >> 1);
            const int d  = n16 + 16 * (mt & 1);
            const float xv = xs[bl * 1024 + s * 32 + d];

            union { short8 s8; __hip_bfloat162 h2[4]; } af;
#pragma unroll
            for (int p = 0; p < 4; ++p) {
                float2 pr = make_float2(xv * yv[mt][2 * p], xv * yv[mt][2 * p + 1]);
                af.h2[p] = __float22bfloat162_rn(pr);
            }
#pragma unroll
            for (int nt = 0; nt < 4; ++nt)
                acc[mt][nt] = __builtin_amdgcn_mfma_f32_16x16x32_bf16(
                    af.s8, bfrag[nt], acc[mt][nt], 0, 0, 0);
        }
    }

    // epilogue: output_mat[b][c][d], d = 16*(mt&1) + quad*4 + t (t-contiguous -> float4)
#pragma unroll
    for (int mt = 0; mt < 4; ++mt) {
        const int b = b0 + (mt >> 1);
        const int dbase = 16 * (mt & 1) + quad * 4;
#pragma unroll
        for (int nt = 0; nt < 4; ++nt) {
            const int c = nt * 16 + n16;
            *(f32x4*)(out_mat + (size_t)b * 2048 + c * 32 + dbase) = acc[mt][nt];
        }
    }

    // final_output[b][c] = sum_d output_mat[b][c][d]
#pragma unroll
    for (int a = 0; a < 2; ++a) {
        const int b = b0 + a;
#pragma unroll
        for (int nt = 0; nt < 4; ++nt) {
            float f = 0.f;
#pragma unroll
            for (int t = 0; t < 4; ++t) f += acc[2 * a][nt][t] + acc[2 * a + 1][nt][t];
            f += __shfl_xor(f, 16);
            f += __shfl_xor(f, 32);
            if (lane < 16) out_fin[(size_t)b * 64 + nt * 16 + n16] = f;
        }
    }
}

extern "C" void kernel_launch(void* const* d_in, const int* in_sizes, int n_in,
                              void* d_out, int out_size, void* d_ws, size_t ws_size,
                              hipStream_t stream) {
    const float* x    = (const float*)d_in[0];   // [4096,32,32]
    const float* y    = (const float*)d_in[1];   // [4096,32,32]
    const float* kern = (const float*)d_in[2];   // [64,32,32]
    float* out_mat = (float*)d_out;                      // [4096,64,32]
    float* out_fin = (float*)d_out + 4096 * 64 * 32;     // [4096,64]
    short* kswz = (short*)d_ws;                          // 65536 bf16 = 128 KB

    kswz_kernel<<<32, 256, 0, stream>>>(kern, kswz);
    cin_main<<<512, 256, 0, stream>>>(x, y, kswz, out_mat, out_fin);
}

// Round 2
// 109.410 us; speedup vs baseline: 1.0278x; 1.0278x over previous
//
#include <hip/hip_runtime.h>
#include <hip/hip_bf16.h>

// GEMM view: Out[(b,d), c] = sum_k A[(b,d),k] * Bk[k,c]
//   row = b*32 + d   (M = 131072)
//   k   = i*32 + j   (K = 1024)  -> MFMA step s covers i=s, j=0..31
//   col = c          (N = 64)
// A[(b,d), i*32+j] = x[b,i,d] * y[b,j,d]  (generated in registers)
// Bk[i*32+j, c]    = kernel[c,i,j]        (pre-swizzled to bf16 B-frag order)
//
// R2: N-split waves (each wave: 4 M-tiles x 2 N-tiles) -> 4096 waves =
// 4 waves/SIMD at constant L2 B-traffic; explicit 1-step prefetch of
// bfrag (global) and x (LDS); kswz re-laid-out so a wave's two N-frags
// are 32B contiguous.

typedef __attribute__((ext_vector_type(8))) short short8;
typedef __attribute__((ext_vector_type(4))) float f32x4;

__device__ __forceinline__ unsigned short f2bf_rne(float f) {
    union { float f; unsigned u; } w; w.f = f;
    return (unsigned short)((w.u + 0x7FFFu + ((w.u >> 16) & 1u)) >> 16);
}

// kswz frag index f = (((s*2 + nth)*64 + lane)*2 + ntl)  (8192 frags of 8 shorts)
// kswz[f*8 + t] = bf16(kernel[c = (nth*2+ntl)*16 + (lane&15)][s][(lane>>4)*8 + t])
__global__ __launch_bounds__(256) void kswz_kernel(const float* __restrict__ kern,
                                                   short* __restrict__ kswz) {
    int f    = blockIdx.x * 256 + threadIdx.x;  // 8192 total
    int ntl  = f & 1;
    int lane = (f >> 1) & 63;
    int nth  = (f >> 7) & 1;
    int s    = f >> 8;
    int c    = (nth * 2 + ntl) * 16 + (lane & 15);
    int jb   = (lane >> 4) * 8;
    const float* src = kern + c * 1024 + s * 32 + jb;
    short8 v;
#pragma unroll
    for (int t = 0; t < 8; ++t) v[t] = (short)f2bf_rne(src[t]);
    *(short8*)(kswz + (size_t)f * 8) = v;
}

// 1024 blocks x 256 threads. Block covers b_blk..b_blk+3 (4 b's), all C.
// Wave w: bpair = w>>1 (2 b's), nth = w&1 (half of C).
__global__ __launch_bounds__(256, 4) void cin_main(const float* __restrict__ x,
                                                   const float* __restrict__ y,
                                                   const short* __restrict__ kswz,
                                                   float* __restrict__ out_mat,
                                                   float* __restrict__ out_fin) {
    __shared__ float xs[4 * 1024];  // 16 KB: x[b_blk..b_blk+4)[i][d]

    const int tid  = threadIdx.x;
    const int wave = tid >> 6;
    const int lane = tid & 63;
    const int quad = lane >> 4;
    const int n16  = lane & 15;
    const int b_blk = blockIdx.x * 4;
    const int bpair = wave >> 1;
    const int nth   = wave & 1;

    // cooperative x stage: 4 * 1024 floats = 1024 float4
    {
        const float4* xg = (const float4*)(x + (size_t)b_blk * 1024);
        float4* xs4 = (float4*)xs;
#pragma unroll
        for (int i = 0; i < 4; ++i) xs4[tid + 256 * i] = xg[tid + 256 * i];
    }

    const int b0 = b_blk + bpair * 2;

    // preload y fragments: yv[mt][t] = y[b, j = quad*8+t, d]
    float yv[4][8];
#pragma unroll
    for (int mt = 0; mt < 4; ++mt) {
        const int b = b0 + (mt >> 1);
        const int d = n16 + 16 * (mt & 1);
        const float* yp = y + (size_t)b * 1024 + (quad * 8) * 32 + d;
#pragma unroll
        for (int t = 0; t < 8; ++t) yv[mt][t] = yp[t * 32];
    }

    f32x4 acc[4][2];
#pragma unroll
    for (int mt = 0; mt < 4; ++mt)
#pragma unroll
        for (int ntl = 0; ntl < 2; ++ntl) acc[mt][ntl] = (f32x4){0.f, 0.f, 0.f, 0.f};

    // wave's kswz base: nth*2048 B + lane*32 B; per-s stride 4096 B
    const char* kb = (const char*)kswz + (size_t)(nth * 2048 + lane * 32);
    // per-mt x base index (floats); per-s stride 32 floats (imm-foldable)
    int xoff[4];
#pragma unroll
    for (int mt = 0; mt < 4; ++mt)
        xoff[mt] = (bpair * 2 + (mt >> 1)) * 1024 + n16 + 16 * (mt & 1);

    __syncthreads();

    // prefetch s = 0
    short8 bc0 = *(const short8*)(kb);
    short8 bc1 = *(const short8*)(kb + 16);
    float xc[4];
#pragma unroll
    for (int mt = 0; mt < 4; ++mt) xc[mt] = xs[xoff[mt]];

#pragma unroll
    for (int s = 0; s < 32; ++s) {
        short8 bn0, bn1;
        float xn[4];
        if (s < 31) {
            bn0 = *(const short8*)(kb + (s + 1) * 4096);
            bn1 = *(const short8*)(kb + (s + 1) * 4096 + 16);
#pragma unroll
            for (int mt = 0; mt < 4; ++mt) xn[mt] = xs[xoff[mt] + (s + 1) * 32];
        }

#pragma unroll
        for (int mt = 0; mt < 4; ++mt) {
            union { short8 s8; __hip_bfloat162 h2[4]; } af;
            const float xv = xc[mt];
#pragma unroll
            for (int p = 0; p < 4; ++p) {
                float2 pr = make_float2(xv * yv[mt][2 * p], xv * yv[mt][2 * p + 1]);
                af.h2[p] = __float22bfloat162_rn(pr);
            }
            acc[mt][0] = __builtin_amdgcn_mfma_f32_16x16x32_bf16(af.s8, bc0, acc[mt][0], 0, 0, 0);
            acc[mt][1] = __builtin_amdgcn_mfma_f32_16x16x32_bf16(af.s8, bc1, acc[mt][1], 0, 0, 0);
        }

        bc0 = bn0; bc1 = bn1;
#pragma unroll
        for (int mt = 0; mt < 4; ++mt) xc[mt] = xn[mt];
    }

    // epilogue: output_mat[b][c][d], d = 16*(mt&1) + quad*4 + t (t-contiguous)
#pragma unroll
    for (int mt = 0; mt < 4; ++mt) {
        const int b = b0 + (mt >> 1);
        const int dbase = 16 * (mt & 1) + quad * 4;
#pragma unroll
        for (int ntl = 0; ntl < 2; ++ntl) {
            const int c = (nth * 2 + ntl) * 16 + n16;
            *(f32x4*)(out_mat + (size_t)b * 2048 + c * 32 + dbase) = acc[mt][ntl];
        }
    }

    // final_output[b][c] = sum_d output_mat[b][c][d]
#pragma unroll
    for (int a = 0; a < 2; ++a) {
        const int b = b0 + a;
#pragma unroll
        for (int ntl = 0; ntl < 2; ++ntl) {
            float f = 0.f;
#pragma unroll
            for (int t = 0; t < 4; ++t) f += acc[2 * a][ntl][t] + acc[2 * a + 1][ntl][t];
            f += __shfl_xor(f, 16);
            f += __shfl_xor(f, 32);
            if (lane < 16) out_fin[(size_t)b * 64 + (nth * 2 + ntl) * 16 + n16] = f;
        }
    }
}

extern "C" void kernel_launch(void* const* d_in, const int* in_sizes, int n_in,
                              void* d_out, int out_size, void* d_ws, size_t ws_size,
                              hipStream_t stream) {
    const float* x    = (const float*)d_in[0];   // [4096,32,32]
    const float* y    = (const float*)d_in[1];   // [4096,32,32]
    const float* kern = (const float*)d_in[2];   // [64,32,32]
    float* out_mat = (float*)d_out;                      // [4096,64,32]
    float* out_fin = (float*)d_out + 4096 * 64 * 32;     // [4096,64]
    short* kswz = (short*)d_ws;                          // 65536 bf16 = 128 KB

    kswz_kernel<<<32, 256, 0, stream>>>(kern, kswz);
    cin_main<<<1024, 256, 0, stream>>>(x, y, kswz, out_mat, out_fin);
}